// Round 2
// baseline (450.481 us; speedup 1.0000x reference)
//
#include <hip/hip_runtime.h>
#include <stdint.h>

typedef _Float16 f16;
typedef _Float16 f16x4 __attribute__((ext_vector_type(4)));
typedef _Float16 f16x8 __attribute__((ext_vector_type(8)));
typedef float f32x4 __attribute__((ext_vector_type(4)));

#define NB 8
#define NN 4096
#define CC 768
#define SCALE_F 0.10206207261596577f  // 96^-0.5

// async global->LDS, 16B per lane; LDS dest = wave-uniform base + lane*16
#define GLDS16(gp, lp)                                                       \
  __builtin_amdgcn_global_load_lds(                                          \
      (__attribute__((address_space(1))) void*)(gp),                         \
      (__attribute__((address_space(3))) void*)(lp), 16, 0, 0)

// ---------------------------------------------------------------------------
// Kernel A: fp32 -> fp16 convert + transpose.
//   x1t[b][c][n] = x1[b][n][c]; x2t[b][d][n] = x2[b][n][d]; x2b = f16(x2)
// 64x64 tiles through LDS (pad 65 to break bank conflicts).
// ---------------------------------------------------------------------------
__global__ __launch_bounds__(256) void k_convert(
    const float* __restrict__ x1, const float* __restrict__ x2,
    f16* __restrict__ x1t, f16* __restrict__ x2t, f16* __restrict__ x2b) {
  __shared__ float tile[64][65];
  const int which = blockIdx.z >> 3;  // 0: x1, 1: x2
  const int b = blockIdx.z & 7;
  const int n0 = blockIdx.x << 6;
  const int c0 = blockIdx.y << 6;
  const float* src = (which ? x2 : x1) + (size_t)b * NN * CC;
  f16* dt = (which ? x2t : x1t) + (size_t)b * CC * NN;
  const int t = threadIdx.x;
  const int rowi = t >> 4;          // 0..15
  const int col4 = (t & 15) << 2;   // 0,4,..,60
#pragma unroll
  for (int it = 0; it < 4; ++it) {
    const int r = it * 16 + rowi;
    const float4 v =
        *reinterpret_cast<const float4*>(&src[(size_t)(n0 + r) * CC + c0 + col4]);
    tile[r][col4 + 0] = v.x;
    tile[r][col4 + 1] = v.y;
    tile[r][col4 + 2] = v.z;
    tile[r][col4 + 3] = v.w;
    if (which) {
      f16x4 o = {(f16)v.x, (f16)v.y, (f16)v.z, (f16)v.w};
      *reinterpret_cast<f16x4*>(
          &x2b[(size_t)b * NN * CC + (size_t)(n0 + r) * CC + c0 + col4]) = o;
    }
  }
  __syncthreads();
  const int c = t >> 2;             // 0..63 (output row within tile)
  const int nb = (t & 3) << 4;      // 0,16,32,48
  f16x8 lo, hi;
#pragma unroll
  for (int j = 0; j < 8; ++j) lo[j] = (f16)tile[nb + j][c];
#pragma unroll
  for (int j = 0; j < 8; ++j) hi[j] = (f16)tile[nb + 8 + j][c];
  f16* o = &dt[(size_t)(c0 + c) * NN + n0 + nb];
  *reinterpret_cast<f16x8*>(o) = lo;
  *reinterpret_cast<f16x8*>(o + 8) = hi;
}

// ---------------------------------------------------------------------------
// Kernel B/D: m97-style bt-GEMM: C[m][n] (+)= sum_k A[m][k]*B[n][k]
// 128x128 tile, BK=32, 4 waves each 64x64 (4x4 of 16x16x32 MFMA).
// ATOMIC=true: split-K accumulation via fp32 atomicAdd (C pre-zeroed).
// ---------------------------------------------------------------------------
template <bool ATOMIC>
__global__ __launch_bounds__(256) void k_gemm_bt(
    const f16* __restrict__ A, const f16* __restrict__ B,
    float* __restrict__ C, int klen, int ksplit, int lda, int ldb, int ldc,
    size_t sA, size_t sB, size_t sC) {
  __shared__ __align__(16) f16 As[128 * 32];
  __shared__ __align__(16) f16 Bs[128 * 32];
  const int z = blockIdx.z;
  const int b = z / ksplit;
  const int ks = z % ksplit;
  const f16* Ap =
      A + (size_t)b * sA + (size_t)blockIdx.y * 128 * lda + (size_t)ks * klen;
  const f16* Bp =
      B + (size_t)b * sB + (size_t)blockIdx.x * 128 * ldb + (size_t)ks * klen;
  float* Cp = C + (size_t)b * sC + (size_t)blockIdx.y * 128 * ldc + blockIdx.x * 128;

  const int tid = threadIdx.x;
  const int wave = tid >> 6;
  const int lane = tid & 63;
  const int wr = wave >> 1;  // wave row (0/1) -> 64-row half
  const int wc = wave & 1;   // wave col (0/1) -> 64-col half

  // staging: wave w loads A rows [32w,32w+32) and B rows [32w,32w+32)
  // lane L -> row +L/4, 16B chunk (L%4) within the 64B (32 f16) row
  const f16* ga0 = Ap + (size_t)(wave * 32 + (lane >> 2)) * lda + (lane & 3) * 8;
  const f16* ga1 = ga0 + (size_t)16 * lda;
  const f16* gb0 = Bp + (size_t)(wave * 32 + (lane >> 2)) * ldb + (lane & 3) * 8;
  const f16* gb1 = gb0 + (size_t)16 * ldb;
  f16* la0 = As + wave * 32 * 32;  // wave-uniform LDS bases
  f16* la1 = la0 + 16 * 32;
  f16* lb0 = Bs + wave * 32 * 32;
  f16* lb1 = lb0 + 16 * 32;

  // fragment read addrs: lane holds row (lane&15), k = (lane>>4)*8 .. +7
  const f16* ra = As + (wr * 64 + (lane & 15)) * 32 + (lane >> 4) * 8;
  const f16* rb = Bs + (wc * 64 + (lane & 15)) * 32 + (lane >> 4) * 8;

  f32x4 acc[4][4] = {};

  for (int k = 0; k < klen; k += 32) {
    __syncthreads();  // previous iter's ds_reads done before overwrite
    GLDS16(ga0, la0);
    GLDS16(ga1, la1);
    GLDS16(gb0, lb0);
    GLDS16(gb1, lb1);
    ga0 += 32; ga1 += 32; gb0 += 32; gb1 += 32;
    __syncthreads();  // drains vmcnt -> staged data visible
    f16x8 af[4], bfv[4];
#pragma unroll
    for (int i = 0; i < 4; ++i)
      af[i] = *reinterpret_cast<const f16x8*>(ra + i * 16 * 32);
#pragma unroll
    for (int j = 0; j < 4; ++j)
      bfv[j] = *reinterpret_cast<const f16x8*>(rb + j * 16 * 32);
#pragma unroll
    for (int i = 0; i < 4; ++i)
#pragma unroll
      for (int j = 0; j < 4; ++j)
        acc[i][j] = __builtin_amdgcn_mfma_f32_16x16x32_f16(af[i], bfv[j],
                                                           acc[i][j], 0, 0, 0);
  }

  // C/D layout (verified m89/m91, dtype-independent): col=lane&15, row=(lane>>4)*4+reg
  const int col = lane & 15;
  const int rq = (lane >> 4) * 4;
#pragma unroll
  for (int i = 0; i < 4; ++i) {
    const int r0 = wr * 64 + i * 16 + rq;
#pragma unroll
    for (int j = 0; j < 4; ++j) {
      const int cidx = wc * 64 + j * 16 + col;
#pragma unroll
      for (int r = 0; r < 4; ++r) {
        const float v = acc[i][j][r];
        if (ATOMIC)
          atomicAdd(&Cp[(size_t)(r0 + r) * ldc + cidx], v);
        else
          Cp[(size_t)(r0 + r) * ldc + cidx] = v;
      }
    }
  }
}

// ---------------------------------------------------------------------------
// Kernel C: row softmax over 768 logits (SCALE applied here), fp32 -> fp16.
// One wave per row, 12 elements/lane, shuffle reductions.
// ---------------------------------------------------------------------------
__global__ __launch_bounds__(256) void k_softmax(const float* __restrict__ S,
                                                 f16* __restrict__ P) {
  const int row = blockIdx.x * 4 + (threadIdx.x >> 6);
  const int lane = threadIdx.x & 63;
  const float* s = S + (size_t)row * CC;
  float v[12];
#pragma unroll
  for (int j = 0; j < 3; ++j) {
    const float4 t = *reinterpret_cast<const float4*>(&s[j * 256 + lane * 4]);
    v[j * 4 + 0] = t.x * SCALE_F;
    v[j * 4 + 1] = t.y * SCALE_F;
    v[j * 4 + 2] = t.z * SCALE_F;
    v[j * 4 + 3] = t.w * SCALE_F;
  }
  float m = v[0];
#pragma unroll
  for (int j = 1; j < 12; ++j) m = fmaxf(m, v[j]);
#pragma unroll
  for (int off = 32; off >= 1; off >>= 1) m = fmaxf(m, __shfl_xor(m, off, 64));
  float sum = 0.f;
#pragma unroll
  for (int j = 0; j < 12; ++j) {
    v[j] = __expf(v[j] - m);
    sum += v[j];
  }
#pragma unroll
  for (int off = 32; off >= 1; off >>= 1) sum += __shfl_xor(sum, off, 64);
  const float inv = 1.0f / sum;
  f16* p = P + (size_t)row * CC;
#pragma unroll
  for (int j = 0; j < 3; ++j) {
    f16x4 o = {(f16)(v[j * 4 + 0] * inv), (f16)(v[j * 4 + 1] * inv),
               (f16)(v[j * 4 + 2] * inv), (f16)(v[j * 4 + 3] * inv)};
    *reinterpret_cast<f16x4*>(&p[j * 256 + lane * 4]) = o;
  }
}

// ---------------------------------------------------------------------------
extern "C" void kernel_launch(void* const* d_in, const int* in_sizes, int n_in,
                              void* d_out, int out_size, void* d_ws,
                              size_t ws_size, hipStream_t stream) {
  const float* x1 = (const float*)d_in[0];
  const float* x2 = (const float*)d_in[1];
  float* out = (float*)d_out;

  const size_t elems = (size_t)NB * NN * CC;  // 25165824
  // x1t/x2t live in d_out (2 * f16 arrays == out fp32 bytes exactly);
  // GEMM2 overwrites out only after GEMM1 consumed them.
  f16* x1t = (f16*)d_out;
  f16* x2t = x1t + elems;
  char* ws = (char*)d_ws;
  f16* x2b = (f16*)ws;                                     // 50.3 MB
  float* S = (float*)(ws + elems * 2);                     // 18.9 MB
  f16* P = (f16*)(ws + elems * 2 + (size_t)NB * CC * CC * 4);  // 9.4 MB
  const size_t need =
      elems * 2 + (size_t)NB * CC * CC * 4 + (size_t)NB * CC * CC * 2;
  if (ws_size < need) return;  // cannot run without scratch

  // A) convert + transpose
  k_convert<<<dim3(NN / 64, CC / 64, 2 * NB), 256, 0, stream>>>(x1, x2, x1t,
                                                                x2t, x2b);
  // B) S = x1t . x2t^T  (split-K x4, atomic accumulate; S pre-zeroed)
  hipMemsetAsync(S, 0, (size_t)NB * CC * CC * 4, stream);
  k_gemm_bt<true><<<dim3(CC / 128, CC / 128, NB * 4), 256, 0, stream>>>(
      x1t, x2t, S, NN / 4, 4, NN, NN, CC, (size_t)CC * NN, (size_t)CC * NN,
      (size_t)CC * CC);
  // C) P = softmax(SCALE * S) as fp16
  k_softmax<<<dim3(NB * CC / 4), 256, 0, stream>>>(S, P);
  // D) out = P . x2b^T
  k_gemm_bt<false><<<dim3(NN / 128, CC / 128, NB), 256, 0, stream>>>(
      P, x2b, out, CC, 1, CC, CC, NN, (size_t)CC * CC, (size_t)NN * CC,
      (size_t)CC * NN);
}

// Round 3
// 428.320 us; speedup vs baseline: 1.0517x; 1.0517x over previous
//
#include <hip/hip_runtime.h>
#include <stdint.h>

typedef _Float16 f16;
typedef _Float16 f16x4 __attribute__((ext_vector_type(4)));
typedef _Float16 f16x8 __attribute__((ext_vector_type(8)));
typedef float f32x4 __attribute__((ext_vector_type(4)));

#define NB 8
#define NN 4096
#define CC 768
#define SCALE_F 0.10206207261596577f  // 96^-0.5

// async global->LDS, 16B per lane; LDS dest = wave-uniform base + lane*16
#define GLDS16(gp, lp)                                                       \
  __builtin_amdgcn_global_load_lds(                                          \
      (__attribute__((address_space(1))) void*)(gp),                         \
      (__attribute__((address_space(3))) void*)(lp), 16, 0, 0)

// ---------------------------------------------------------------------------
// Kernel A: fp32 -> fp16 convert + transpose.
//   x1t[b][c][n] = x1[b][n][c]; x2t[b][d][n] = x2[b][n][d]; x2b = f16(x2)
// ---------------------------------------------------------------------------
__global__ __launch_bounds__(256) void k_convert(
    const float* __restrict__ x1, const float* __restrict__ x2,
    f16* __restrict__ x1t, f16* __restrict__ x2t, f16* __restrict__ x2b) {
  __shared__ float tile[64][65];
  const int which = blockIdx.z >> 3;  // 0: x1, 1: x2
  const int b = blockIdx.z & 7;
  const int n0 = blockIdx.x << 6;
  const int c0 = blockIdx.y << 6;
  const float* src = (which ? x2 : x1) + (size_t)b * NN * CC;
  f16* dt = (which ? x2t : x1t) + (size_t)b * CC * NN;
  const int t = threadIdx.x;
  const int rowi = t >> 4;          // 0..15
  const int col4 = (t & 15) << 2;   // 0,4,..,60
#pragma unroll
  for (int it = 0; it < 4; ++it) {
    const int r = it * 16 + rowi;
    const float4 v =
        *reinterpret_cast<const float4*>(&src[(size_t)(n0 + r) * CC + c0 + col4]);
    tile[r][col4 + 0] = v.x;
    tile[r][col4 + 1] = v.y;
    tile[r][col4 + 2] = v.z;
    tile[r][col4 + 3] = v.w;
    if (which) {
      f16x4 o = {(f16)v.x, (f16)v.y, (f16)v.z, (f16)v.w};
      *reinterpret_cast<f16x4*>(
          &x2b[(size_t)b * NN * CC + (size_t)(n0 + r) * CC + c0 + col4]) = o;
    }
  }
  __syncthreads();
  const int c = t >> 2;             // 0..63 (output row within tile)
  const int nb = (t & 3) << 4;      // 0,16,32,48
  f16x8 lo, hi;
#pragma unroll
  for (int j = 0; j < 8; ++j) lo[j] = (f16)tile[nb + j][c];
#pragma unroll
  for (int j = 0; j < 8; ++j) hi[j] = (f16)tile[nb + 8 + j][c];
  f16* o = &dt[(size_t)(c0 + c) * NN + n0 + nb];
  *reinterpret_cast<f16x8*>(o) = lo;
  *reinterpret_cast<f16x8*>(o + 8) = hi;
}

// ---------------------------------------------------------------------------
// Kernel B/D: m97-style bt-GEMM: C[m][n] (+)= sum_k A[m][k]*B[n][k]
// 128x128 tile, BK=32, 4 waves each 64x64 (4x4 of 16x16x32 MFMA).
// 1-D grid + XCD-locality swizzle (assumes hw xcd = blockIdx.x % 8):
//  SWZ=1 (GEMM1): 6x6 tiles, 8 batches, ksplit=4. batch = xcd; the 4 K-splits
//                 run sequentially per XCD -> (b,ks) working set 3 MB < 4 MB L2.
//  SWZ=2 (GEMM2): 32x6 tiles, 8 batches. batch = xcd; 6 row-tiles sharing a
//                 B n-chunk are consecutive slots; A (1.2 MB) stays L2-hot.
// ---------------------------------------------------------------------------
template <bool ATOMIC, int SWZ>
__global__ __launch_bounds__(256) void k_gemm_bt(
    const f16* __restrict__ A, const f16* __restrict__ B,
    float* __restrict__ C, int klen, int lda, int ldb, int ldc,
    size_t sA, size_t sB, size_t sC) {
  __shared__ __align__(16) f16 As[128 * 32];
  __shared__ __align__(16) f16 Bs[128 * 32];

  const int lin = blockIdx.x;
  const int xcd = lin & 7;
  const int slot = lin >> 3;
  int bx, by, b, ks;
  if (SWZ == 1) {
    b = xcd;                 // one batch per XCD
    ks = slot / 36;          // 4 sequential K-split phases
    const int item = slot % 36;
    bx = item % 6;
    by = item / 6;
  } else {
    b = xcd;                 // one batch per XCD
    ks = 0;
    bx = slot / 6;           // B n-chunk index (streamed)
    by = slot % 6;           // 6 consecutive tiles share the B chunk
  }

  const f16* Ap = A + (size_t)b * sA + (size_t)by * 128 * lda + (size_t)ks * klen;
  const f16* Bp = B + (size_t)b * sB + (size_t)bx * 128 * ldb + (size_t)ks * klen;
  float* Cp = C + (size_t)b * sC + (size_t)by * 128 * ldc + bx * 128;

  const int tid = threadIdx.x;
  const int wave = tid >> 6;
  const int lane = tid & 63;
  const int wr = wave >> 1;  // wave row (0/1) -> 64-row half
  const int wc = wave & 1;   // wave col (0/1) -> 64-col half

  // staging: wave w loads A rows [32w,32w+32) and B rows [32w,32w+32)
  const f16* ga0 = Ap + (size_t)(wave * 32 + (lane >> 2)) * lda + (lane & 3) * 8;
  const f16* ga1 = ga0 + (size_t)16 * lda;
  const f16* gb0 = Bp + (size_t)(wave * 32 + (lane >> 2)) * ldb + (lane & 3) * 8;
  const f16* gb1 = gb0 + (size_t)16 * ldb;
  f16* la0 = As + wave * 32 * 32;  // wave-uniform LDS bases
  f16* la1 = la0 + 16 * 32;
  f16* lb0 = Bs + wave * 32 * 32;
  f16* lb1 = lb0 + 16 * 32;

  // fragment read addrs: lane holds row (lane&15), k = (lane>>4)*8 .. +7
  const f16* ra = As + (wr * 64 + (lane & 15)) * 32 + (lane >> 4) * 8;
  const f16* rb = Bs + (wc * 64 + (lane & 15)) * 32 + (lane >> 4) * 8;

  f32x4 acc[4][4] = {};

  for (int k = 0; k < klen; k += 32) {
    __syncthreads();  // previous iter's ds_reads done before overwrite
    GLDS16(ga0, la0);
    GLDS16(ga1, la1);
    GLDS16(gb0, lb0);
    GLDS16(gb1, lb1);
    ga0 += 32; ga1 += 32; gb0 += 32; gb1 += 32;
    __syncthreads();  // drains vmcnt -> staged data visible
    f16x8 af[4], bfv[4];
#pragma unroll
    for (int i = 0; i < 4; ++i)
      af[i] = *reinterpret_cast<const f16x8*>(ra + i * 16 * 32);
#pragma unroll
    for (int j = 0; j < 4; ++j)
      bfv[j] = *reinterpret_cast<const f16x8*>(rb + j * 16 * 32);
#pragma unroll
    for (int i = 0; i < 4; ++i)
#pragma unroll
      for (int j = 0; j < 4; ++j)
        acc[i][j] = __builtin_amdgcn_mfma_f32_16x16x32_f16(af[i], bfv[j],
                                                           acc[i][j], 0, 0, 0);
  }

  // C/D layout (verified m89/m91, dtype-independent): col=lane&15, row=(lane>>4)*4+reg
  const int col = lane & 15;
  const int rq = (lane >> 4) * 4;
#pragma unroll
  for (int i = 0; i < 4; ++i) {
    const int r0 = wr * 64 + i * 16 + rq;
#pragma unroll
    for (int j = 0; j < 4; ++j) {
      const int cidx = wc * 64 + j * 16 + col;
#pragma unroll
      for (int r = 0; r < 4; ++r) {
        const float v = acc[i][j][r];
        if (ATOMIC)
          atomicAdd(&Cp[(size_t)(r0 + r) * ldc + cidx], v);
        else
          Cp[(size_t)(r0 + r) * ldc + cidx] = v;
      }
    }
  }
}

// ---------------------------------------------------------------------------
// Kernel C: row softmax over 768 logits (SCALE applied here), fp32 -> fp16.
// ---------------------------------------------------------------------------
__global__ __launch_bounds__(256) void k_softmax(const float* __restrict__ S,
                                                 f16* __restrict__ P) {
  const int row = blockIdx.x * 4 + (threadIdx.x >> 6);
  const int lane = threadIdx.x & 63;
  const float* s = S + (size_t)row * CC;
  float v[12];
#pragma unroll
  for (int j = 0; j < 3; ++j) {
    const float4 t = *reinterpret_cast<const float4*>(&s[j * 256 + lane * 4]);
    v[j * 4 + 0] = t.x * SCALE_F;
    v[j * 4 + 1] = t.y * SCALE_F;
    v[j * 4 + 2] = t.z * SCALE_F;
    v[j * 4 + 3] = t.w * SCALE_F;
  }
  float m = v[0];
#pragma unroll
  for (int j = 1; j < 12; ++j) m = fmaxf(m, v[j]);
#pragma unroll
  for (int off = 32; off >= 1; off >>= 1) m = fmaxf(m, __shfl_xor(m, off, 64));
  float sum = 0.f;
#pragma unroll
  for (int j = 0; j < 12; ++j) {
    v[j] = __expf(v[j] - m);
    sum += v[j];
  }
#pragma unroll
  for (int off = 32; off >= 1; off >>= 1) sum += __shfl_xor(sum, off, 64);
  const float inv = 1.0f / sum;
  f16* p = P + (size_t)row * CC;
#pragma unroll
  for (int j = 0; j < 3; ++j) {
    f16x4 o = {(f16)(v[j * 4 + 0] * inv), (f16)(v[j * 4 + 1] * inv),
               (f16)(v[j * 4 + 2] * inv), (f16)(v[j * 4 + 3] * inv)};
    *reinterpret_cast<f16x4*>(&p[j * 256 + lane * 4]) = o;
  }
}

// ---------------------------------------------------------------------------
extern "C" void kernel_launch(void* const* d_in, const int* in_sizes, int n_in,
                              void* d_out, int out_size, void* d_ws,
                              size_t ws_size, hipStream_t stream) {
  const float* x1 = (const float*)d_in[0];
  const float* x2 = (const float*)d_in[1];
  float* out = (float*)d_out;

  const size_t elems = (size_t)NB * NN * CC;  // 25165824
  // x1t/x2t live in d_out (2 * f16 arrays == out fp32 bytes exactly);
  // GEMM2 overwrites out only after GEMM1 consumed them.
  f16* x1t = (f16*)d_out;
  f16* x2t = x1t + elems;
  char* ws = (char*)d_ws;
  f16* x2b = (f16*)ws;                                     // 50.3 MB
  float* S = (float*)(ws + elems * 2);                     // 18.9 MB
  f16* P = (f16*)(ws + elems * 2 + (size_t)NB * CC * CC * 4);  // 9.4 MB
  const size_t need =
      elems * 2 + (size_t)NB * CC * CC * 4 + (size_t)NB * CC * CC * 2;
  if (ws_size < need) return;  // cannot run without scratch

  // A) convert + transpose
  k_convert<<<dim3(NN / 64, CC / 64, 2 * NB), 256, 0, stream>>>(x1, x2, x1t,
                                                                x2t, x2b);
  // B) S = x1t . x2t^T  (split-K x4, atomic accumulate; S pre-zeroed)
  hipMemsetAsync(S, 0, (size_t)NB * CC * CC * 4, stream);
  k_gemm_bt<true, 1><<<dim3(6 * 6 * NB * 4), 256, 0, stream>>>(
      x1t, x2t, S, NN / 4, NN, NN, CC, (size_t)CC * NN, (size_t)CC * NN,
      (size_t)CC * CC);
  // C) P = softmax(SCALE * S) as fp16
  k_softmax<<<dim3(NB * CC / 4), 256, 0, stream>>>(S, P);
  // D) out = P . x2b^T
  k_gemm_bt<false, 2><<<dim3(32 * 6 * NB), 256, 0, stream>>>(
      P, x2b, out, CC, CC, CC, NN, (size_t)CC * CC, (size_t)NN * CC,
      (size_t)CC * NN);
}

// Round 4
// 424.260 us; speedup vs baseline: 1.0618x; 1.0096x over previous
//
#include <hip/hip_runtime.h>
#include <stdint.h>

typedef _Float16 f16;
typedef _Float16 f16x4 __attribute__((ext_vector_type(4)));
typedef _Float16 f16x8 __attribute__((ext_vector_type(8)));
typedef float f32x4 __attribute__((ext_vector_type(4)));

#define NB 8
#define NN 4096
#define CC 768
#define SCALE_F 0.10206207261596577f  // 96^-0.5

// async global->LDS, 16B per lane; LDS dest = wave-uniform base + lane*16
#define GLDS16(gp, lp)                                                       \
  __builtin_amdgcn_global_load_lds(                                          \
      (__attribute__((address_space(1))) void*)(gp),                         \
      (__attribute__((address_space(3))) void*)(lp), 16, 0, 0)

// ---------------------------------------------------------------------------
// Kernel A: fp32 -> fp16 convert + transpose.
//   x1t[b][c][n] = x1[b][n][c]; x2t[b][d][n] = x2[b][n][d]; x2b = f16(x2)
// ---------------------------------------------------------------------------
__global__ __launch_bounds__(256) void k_convert(
    const float* __restrict__ x1, const float* __restrict__ x2,
    f16* __restrict__ x1t, f16* __restrict__ x2t, f16* __restrict__ x2b) {
  __shared__ float tile[64][65];
  const int which = blockIdx.z >> 3;  // 0: x1, 1: x2
  const int b = blockIdx.z & 7;
  const int n0 = blockIdx.x << 6;
  const int c0 = blockIdx.y << 6;
  const float* src = (which ? x2 : x1) + (size_t)b * NN * CC;
  f16* dt = (which ? x2t : x1t) + (size_t)b * CC * NN;
  const int t = threadIdx.x;
  const int rowi = t >> 4;          // 0..15
  const int col4 = (t & 15) << 2;   // 0,4,..,60
#pragma unroll
  for (int it = 0; it < 4; ++it) {
    const int r = it * 16 + rowi;
    const float4 v =
        *reinterpret_cast<const float4*>(&src[(size_t)(n0 + r) * CC + c0 + col4]);
    tile[r][col4 + 0] = v.x;
    tile[r][col4 + 1] = v.y;
    tile[r][col4 + 2] = v.z;
    tile[r][col4 + 3] = v.w;
    if (which) {
      f16x4 o = {(f16)v.x, (f16)v.y, (f16)v.z, (f16)v.w};
      *reinterpret_cast<f16x4*>(
          &x2b[(size_t)b * NN * CC + (size_t)(n0 + r) * CC + c0 + col4]) = o;
    }
  }
  __syncthreads();
  const int c = t >> 2;             // 0..63 (output row within tile)
  const int nb = (t & 3) << 4;      // 0,16,32,48
  f16x8 lo, hi;
#pragma unroll
  for (int j = 0; j < 8; ++j) lo[j] = (f16)tile[nb + j][c];
#pragma unroll
  for (int j = 0; j < 8; ++j) hi[j] = (f16)tile[nb + 8 + j][c];
  f16* o = &dt[(size_t)(c0 + c) * NN + n0 + nb];
  *reinterpret_cast<f16x8*>(o) = lo;
  *reinterpret_cast<f16x8*>(o + 8) = hi;
}

// ---------------------------------------------------------------------------
// Kernel B/D: bt-GEMM: C[m][n] (+)= sum_k A[m][k]*B[n][k]
// 128x128 tile, BK=32, 4 waves each 64x64 (4x4 of 16x16x32 MFMA).
// Ping-pong LDS double-buffer: prefetch tile k+1 issued right after the
// single per-iter barrier, so its latency overlaps tile k's ds_read+MFMA.
// The compiler's barrier drain (vmcnt(0)+lgkmcnt(0)) provides both the
// prefetch-complete and buffer-reuse guarantees.
// 1-D grid + XCD-locality swizzle (assumes hw xcd = blockIdx.x % 8):
//  SWZ=1 (GEMM1): 6x6 tiles, 8 batches, ksplit=4; batch = xcd.
//  SWZ=2 (GEMM2): 32x6 tiles, 8 batches; batch = xcd.
// ---------------------------------------------------------------------------
template <bool ATOMIC, int SWZ>
__global__ __launch_bounds__(256) void k_gemm_bt(
    const f16* __restrict__ A, const f16* __restrict__ B,
    float* __restrict__ C, int klen, int lda, int ldb, int ldc,
    size_t sA, size_t sB, size_t sC) {
  __shared__ __align__(16) f16 As[2][128 * 32];
  __shared__ __align__(16) f16 Bs[2][128 * 32];

  const int lin = blockIdx.x;
  const int xcd = lin & 7;
  const int slot = lin >> 3;
  int bx, by, b, ks;
  if (SWZ == 1) {
    b = xcd;                 // one batch per XCD
    ks = slot / 36;          // 4 sequential K-split phases
    const int item = slot % 36;
    bx = item % 6;
    by = item / 6;
  } else {
    b = xcd;                 // one batch per XCD
    ks = 0;
    bx = slot / 6;           // B n-chunk index (streamed)
    by = slot % 6;           // 6 consecutive tiles share the B chunk
  }

  const f16* Ap = A + (size_t)b * sA + (size_t)by * 128 * lda + (size_t)ks * klen;
  const f16* Bp = B + (size_t)b * sB + (size_t)bx * 128 * ldb + (size_t)ks * klen;
  float* Cp = C + (size_t)b * sC + (size_t)by * 128 * ldc + bx * 128;

  const int tid = threadIdx.x;
  const int wave = tid >> 6;
  const int lane = tid & 63;
  const int wr = wave >> 1;  // wave row (0/1) -> 64-row half
  const int wc = wave & 1;   // wave col (0/1) -> 64-col half

  // staging: wave w loads A rows [32w,32w+32) and B rows [32w,32w+32)
  const f16* ga0 = Ap + (size_t)(wave * 32 + (lane >> 2)) * lda + (lane & 3) * 8;
  const f16* ga1 = ga0 + (size_t)16 * lda;
  const f16* gb0 = Bp + (size_t)(wave * 32 + (lane >> 2)) * ldb + (lane & 3) * 8;
  const f16* gb1 = gb0 + (size_t)16 * ldb;
  const int lofs0 = wave * 32 * 32;       // wave-uniform LDS offsets
  const int lofs1 = lofs0 + 16 * 32;

  // fragment read offsets: lane holds row (lane&15), k = (lane>>4)*8 .. +7
  const int raofs = (wr * 64 + (lane & 15)) * 32 + (lane >> 4) * 8;
  const int rbofs = (wc * 64 + (lane & 15)) * 32 + (lane >> 4) * 8;

  f32x4 acc[4][4] = {};

  const int nit = klen >> 5;
  // prologue: stage tile 0 into buffer 0
  GLDS16(ga0, &As[0][lofs0]);
  GLDS16(ga1, &As[0][lofs1]);
  GLDS16(gb0, &Bs[0][lofs0]);
  GLDS16(gb1, &Bs[0][lofs1]);

  for (int it = 0; it < nit; ++it) {
    const int cur = it & 1;
    const int nxt = cur ^ 1;
    __syncthreads();  // vmcnt(0): tile-it prefetch done; lgkmcnt(0): buf[nxt] readers done
    if (it + 1 < nit) {
      ga0 += 32; ga1 += 32; gb0 += 32; gb1 += 32;
      GLDS16(ga0, &As[nxt][lofs0]);
      GLDS16(ga1, &As[nxt][lofs1]);
      GLDS16(gb0, &Bs[nxt][lofs0]);
      GLDS16(gb1, &Bs[nxt][lofs1]);
    }
    const f16* ra = &As[cur][raofs];
    const f16* rb = &Bs[cur][rbofs];
    f16x8 af[4], bfv[4];
#pragma unroll
    for (int i = 0; i < 4; ++i)
      af[i] = *reinterpret_cast<const f16x8*>(ra + i * 16 * 32);
#pragma unroll
    for (int j = 0; j < 4; ++j)
      bfv[j] = *reinterpret_cast<const f16x8*>(rb + j * 16 * 32);
#pragma unroll
    for (int i = 0; i < 4; ++i)
#pragma unroll
      for (int j = 0; j < 4; ++j)
        acc[i][j] = __builtin_amdgcn_mfma_f32_16x16x32_f16(af[i], bfv[j],
                                                           acc[i][j], 0, 0, 0);
  }

  // C/D layout (verified m89/m91, dtype-independent): col=lane&15, row=(lane>>4)*4+reg
  const int col = lane & 15;
  const int rq = (lane >> 4) * 4;
#pragma unroll
  for (int i = 0; i < 4; ++i) {
    const int r0 = wr * 64 + i * 16 + rq;
#pragma unroll
    for (int j = 0; j < 4; ++j) {
      const int cidx = wc * 64 + j * 16 + col;
#pragma unroll
      for (int r = 0; r < 4; ++r) {
        const float v = acc[i][j][r];
        if (ATOMIC)
          atomicAdd(&Cp[(size_t)(r0 + r) * ldc + cidx], v);
        else
          Cp[(size_t)(r0 + r) * ldc + cidx] = v;
      }
    }
  }
}

// ---------------------------------------------------------------------------
// Kernel C: row softmax over 768 logits (SCALE applied here), fp32 -> fp16.
// ---------------------------------------------------------------------------
__global__ __launch_bounds__(256) void k_softmax(const float* __restrict__ S,
                                                 f16* __restrict__ P) {
  const int row = blockIdx.x * 4 + (threadIdx.x >> 6);
  const int lane = threadIdx.x & 63;
  const float* s = S + (size_t)row * CC;
  float v[12];
#pragma unroll
  for (int j = 0; j < 3; ++j) {
    const float4 t = *reinterpret_cast<const float4*>(&s[j * 256 + lane * 4]);
    v[j * 4 + 0] = t.x * SCALE_F;
    v[j * 4 + 1] = t.y * SCALE_F;
    v[j * 4 + 2] = t.z * SCALE_F;
    v[j * 4 + 3] = t.w * SCALE_F;
  }
  float m = v[0];
#pragma unroll
  for (int j = 1; j < 12; ++j) m = fmaxf(m, v[j]);
#pragma unroll
  for (int off = 32; off >= 1; off >>= 1) m = fmaxf(m, __shfl_xor(m, off, 64));
  float sum = 0.f;
#pragma unroll
  for (int j = 0; j < 12; ++j) {
    v[j] = __expf(v[j] - m);
    sum += v[j];
  }
#pragma unroll
  for (int off = 32; off >= 1; off >>= 1) sum += __shfl_xor(sum, off, 64);
  const float inv = 1.0f / sum;
  f16* p = P + (size_t)row * CC;
#pragma unroll
  for (int j = 0; j < 3; ++j) {
    f16x4 o = {(f16)(v[j * 4 + 0] * inv), (f16)(v[j * 4 + 1] * inv),
               (f16)(v[j * 4 + 2] * inv), (f16)(v[j * 4 + 3] * inv)};
    *reinterpret_cast<f16x4*>(&p[j * 256 + lane * 4]) = o;
  }
}

// ---------------------------------------------------------------------------
extern "C" void kernel_launch(void* const* d_in, const int* in_sizes, int n_in,
                              void* d_out, int out_size, void* d_ws,
                              size_t ws_size, hipStream_t stream) {
  const float* x1 = (const float*)d_in[0];
  const float* x2 = (const float*)d_in[1];
  float* out = (float*)d_out;

  const size_t elems = (size_t)NB * NN * CC;  // 25165824
  // x1t/x2t live in d_out (2 * f16 arrays == out fp32 bytes exactly);
  // GEMM2 overwrites out only after GEMM1 consumed them.
  f16* x1t = (f16*)d_out;
  f16* x2t = x1t + elems;
  char* ws = (char*)d_ws;
  f16* x2b = (f16*)ws;                                     // 50.3 MB
  float* S = (float*)(ws + elems * 2);                     // 18.9 MB
  f16* P = (f16*)(ws + elems * 2 + (size_t)NB * CC * CC * 4);  // 9.4 MB
  const size_t need =
      elems * 2 + (size_t)NB * CC * CC * 4 + (size_t)NB * CC * CC * 2;
  if (ws_size < need) return;  // cannot run without scratch

  // A) convert + transpose
  k_convert<<<dim3(NN / 64, CC / 64, 2 * NB), 256, 0, stream>>>(x1, x2, x1t,
                                                                x2t, x2b);
  // B) S = x1t . x2t^T  (split-K x4, atomic accumulate; S pre-zeroed)
  hipMemsetAsync(S, 0, (size_t)NB * CC * CC * 4, stream);
  k_gemm_bt<true, 1><<<dim3(6 * 6 * NB * 4), 256, 0, stream>>>(
      x1t, x2t, S, NN / 4, NN, NN, CC, (size_t)CC * NN, (size_t)CC * NN,
      (size_t)CC * CC);
  // C) P = softmax(SCALE * S) as fp16
  k_softmax<<<dim3(NB * CC / 4), 256, 0, stream>>>(S, P);
  // D) out = P . x2b^T
  k_gemm_bt<false, 2><<<dim3(32 * 6 * NB), 256, 0, stream>>>(
      P, x2b, out, CC, CC, CC, NN, (size_t)CC * CC, (size_t)NN * CC,
      (size_t)CC * NN);
}